// Round 12
// baseline (219.942 us; speedup 1.0000x reference)
//
#include <hip/hip_runtime.h>
#include <math.h>

// DigitCaps dynamic routing, MI355X (gfx950). Round 12: R11 + fewer barriers
// + 5 resident blocks/CU. B=256, I=1152 (dim 8), O=10 (dim 16), 3 iters.
//
// R11 measured: k_pass 49 us, VALUBusy 57-60%, occ 31%, VGPR 60, FETCH 8 MB
// (W L2-hot; compiler reloads W per bb rather than pinning wr[20] — fine).
// Stall causes: 3 makespan rounds (9 blocks/CU, cap 4) + 8 barriers/kernel.
// This round: pacc[4][8][160] (20 KB) with ONE flush (2 barriers total);
// launch_bounds(256,5) — safe because live VGPR is 60 << 102 budget
// (R6/R7 spills happened when live state needed > the shrunken budget).
// LDS = 4 + 20 + 5 = 29 KB -> 5 blocks/CU; rounds ceil(9/5) = 2.
//
// b_ij identity: logits at iter k = u.(v0+..+v_{k-1}) = u.vsum.
// Pipeline: k_pass<0> -> k_squash<0>(pre=0.1) -> k_pass<1> -> k_squash<1>
//           -> k_pass<1> -> k_squash<2> -> out.

constexpr int Bc  = 256;
constexpr int Ic  = 1152;
constexpr int Oc  = 10;
constexpr int DOc = 16;
constexpr int ODc = 160;
constexpr int ITILES = 72;
constexpr int BB  = 8;               // b per block
constexpr int BT  = Bc / BB;         // 32 btiles

// Sum over the aligned 16-lane group, result in all 16 lanes. Pure VALU (DPP).
__device__ __forceinline__ float dpp16_sum(float v) {
    int s;
    s = __builtin_amdgcn_update_dpp(0, __float_as_int(v), 0xB1, 0xF, 0xF, true);
    v += __int_as_float(s);
    s = __builtin_amdgcn_update_dpp(0, __float_as_int(v), 0x4E, 0xF, 0xF, true);
    v += __int_as_float(s);
    s = __builtin_amdgcn_update_dpp(0, __float_as_int(v), 0x124, 0xF, 0xF, true);
    v += __int_as_float(s);
    s = __builtin_amdgcn_update_dpp(0, __float_as_int(v), 0x128, 0xF, 0xF, true);
    v += __int_as_float(s);
    return v;
}

// ---------------------------------------------------------------- k_pass
// grid 2304 = 72 itiles x 32 btiles, 256 threads, launch_bounds(256,5).
// Thread (il = t>>4, d = t&15) owns capsule i = itile*16+il, out-dim d over
// the btile's 8 b. W rows come from L2 (itile%8 pins the W slice to one XCD).
// PASS 0: contrib = u (0.1 folded into squash).  PASS 1: softmax routing.
template <int PASS>
__global__ __launch_bounds__(256, 5) void k_pass(const float* __restrict__ x,
                                                 const float* __restrict__ W,
                                                 const float* __restrict__ vsum,
                                                 float* __restrict__ partial) {
    const int bx    = blockIdx.x;
    const int itile = bx % ITILES;      // 72%8==0: itile pinned to an XCD
    const int btile = bx / ITILES;
    const int t     = threadIdx.x;
    const int d     = t & 15;
    const int il    = t >> 4;
    const int w     = t >> 6;
    const int i     = itile * 16 + il;
    const int b0    = btile * BB;

    __shared__ __align__(16) float xs[BB * 128];       //  4 KB [bb][il*8+k]
    __shared__ __align__(16) float pacc[4 * BB * ODc]; // 20 KB [w][bb][od]
    __shared__ __align__(16) float vs_s[BB * ODc];     //  5 KB [bb][od]

    // stage x[b0:b0+8][itile*16:+16][8]: 256 float4, one per thread
    {
        int bb = t >> 5;
        int r  = t & 31;
        ((float4*)xs)[t] =
            ((const float4*)(x + (size_t)(b0 + bb) * (Ic * 8) + itile * 128))[r];
    }
    if (PASS == 1) {
        // vsum rows for b0..b0+7: 1280 floats = 320 float4
        const float4* vg = (const float4*)(vsum + (size_t)b0 * ODc);
#pragma unroll
        for (int j = 0; j < 2; ++j) {
            int e = t + j * 256;
            if (e < 320) ((float4*)vs_s)[e] = vg[e];
        }
    }

    // W fragment for (i, d): 10 o x 8 k = 80 floats (L1/L2-hot reuse)
    float4 wr[20];
    {
        const float4* wp = (const float4*)(W + (((size_t)i * Oc) * DOc + d) * 8);
#pragma unroll
        for (int o = 0; o < Oc; ++o) {
            wr[2 * o]     = wp[o * 32];
            wr[2 * o + 1] = wp[o * 32 + 1];
        }
    }
    __syncthreads();

#pragma unroll 1
    for (int bb = 0; bb < BB; ++bb) {
        const float4 xa = *((const float4*)(xs + bb * 128 + il * 8));
        const float4 xb = *((const float4*)(xs + bb * 128 + il * 8 + 4));
        float u[Oc];
#pragma unroll
        for (int o = 0; o < Oc; ++o) {
            float4 w0 = wr[2 * o], w1 = wr[2 * o + 1];
            u[o] = w0.x * xa.x + w0.y * xa.y + w0.z * xa.z + w0.w * xa.w +
                   w1.x * xb.x + w1.y * xb.y + w1.z * xb.z + w1.w * xb.w;
        }
        float contrib[Oc];
        if (PASS == 1) {
            // logits via DPP 16-lane reduce (VALU, no DS traffic)
            float c[Oc];
#pragma unroll
            for (int o = 0; o < Oc; ++o)
                c[o] = dpp16_sum(u[o] * vs_s[bb * ODc + o * 16 + d]);
            float m = c[0];
#pragma unroll
            for (int o = 1; o < Oc; ++o) m = fmaxf(m, c[o]);
            float se = 0.f;
#pragma unroll
            for (int o = 0; o < Oc; ++o) {
                c[o] = __expf(c[o] - m);
                se += c[o];
            }
            const float inv = 1.f / se;
#pragma unroll
            for (int o = 0; o < Oc; ++o) contrib[o] = (c[o] * inv) * u[o];
        } else {
            // iter 0: softmax(0)=1/10 exactly; 0.1 folded into squash pre.
#pragma unroll
            for (int o = 0; o < Oc; ++o) contrib[o] = u[o];
        }
        // in-wave il-reduce; lanes<16 hold the (o,d) sums for this bb
#pragma unroll
        for (int o = 0; o < Oc; ++o) {
            float a = contrib[o];
            a += __shfl_xor(a, 16);
            a += __shfl_xor(a, 32);
            if ((t & 63) < 16) pacc[(w * BB + bb) * ODc + o * 16 + d] = a;
        }
    }
    __syncthreads();
    // single flush: 8 bb x 160 od = 1280 floats, 5 per thread
#pragma unroll
    for (int j = 0; j < 5; ++j) {
        int e = t + j * 256;              // bb*160 + od
        float s = pacc[e] + pacc[BB * ODc + e] + pacc[2 * BB * ODc + e] +
                  pacc[3 * BB * ODc + e];
        partial[(size_t)itile * (Bc * ODc) + b0 * ODc + e] = s;
    }
}

// ---------------------------------------------------------------- k_squash
// MODE 0: vsum = v   MODE 1: vsum += v   MODE 2: out = v
template <int MODE>
__global__ __launch_bounds__(256) void k_squash(const float* __restrict__ part,
                                                float* __restrict__ vsum,
                                                float* __restrict__ out,
                                                float pre) {
    const int b = blockIdx.x;
    const int t = threadIdx.x;
    if (t >= ODc) return;
    float s = 0.f;
#pragma unroll 8
    for (int p = 0; p < ITILES; ++p)
        s += part[(size_t)p * (Bc * ODc) + b * ODc + t];
    s *= pre;
    float sq = dpp16_sum(s * s);
    float scale = sq / ((1.f + sq) * sqrtf(sq));
    float v = s * scale;
    if (MODE == 0) vsum[b * ODc + t] = v;
    if (MODE == 1) vsum[b * ODc + t] += v;
    if (MODE == 2) out[(size_t)b * ODc + t] = v;
}

// ---------------------------------------------------------------- fallback
__global__ void __launch_bounds__(1024, 4)
digitcaps_fallback(const float* __restrict__ x, const float* __restrict__ W,
                   float* __restrict__ out) {
    const int b = blockIdx.x, t = threadIdx.x;
    const int lane = t & 63, wid = t >> 6, d = t & 15, iblk = t >> 4;
    __shared__ __align__(16) float xs[Ic * 8];
    __shared__ __align__(16) float red[16 * ODc];
    __shared__ __align__(16) float svec[ODc], vcur[ODc], vsum[ODc];
    {
        const float4* xg = (const float4*)(x + (size_t)b * (Ic * 8));
        float4* xl = (float4*)xs;
        for (int j = t; j < Ic * 2; j += 1024) xl[j] = xg[j];
    }
    if (t < ODc) vsum[t] = 0.f;
    __syncthreads();
    float acc[Oc], vsr[Oc];
    for (int it = 0; it < 3; ++it) {
#pragma unroll
        for (int o = 0; o < Oc; ++o) { acc[o] = 0.f; vsr[o] = vsum[o * 16 + d]; }
#pragma unroll 1
        for (int chk = 0; chk < 18; ++chk) {
            const int i = chk * 64 + iblk;
            const float4 xa = ((const float4*)(xs + i * 8))[0];
            const float4 xb = ((const float4*)(xs + i * 8))[1];
            const float* wb = W + (((size_t)i * Oc) * DOc + d) * 8;
            float uo[Oc];
#pragma unroll
            for (int o = 0; o < Oc; ++o) {
                const float4* wp = (const float4*)(wb + o * 128);
                float4 w0 = wp[0], w1 = wp[1];
                uo[o] = w0.x * xa.x + w0.y * xa.y + w0.z * xa.z + w0.w * xa.w +
                        w1.x * xb.x + w1.y * xb.y + w1.z * xb.z + w1.w * xb.w;
            }
            float cc[Oc];
            if (it > 0) {
#pragma unroll
                for (int o = 0; o < Oc; ++o) cc[o] = dpp16_sum(uo[o] * vsr[o]);
                float m = cc[0];
#pragma unroll
                for (int o = 1; o < Oc; ++o) m = fmaxf(m, cc[o]);
                float se = 0.f;
#pragma unroll
                for (int o = 0; o < Oc; ++o) { cc[o] = __expf(cc[o] - m); se += cc[o]; }
                float inv = 1.f / se;
#pragma unroll
                for (int o = 0; o < Oc; ++o) acc[o] += cc[o] * inv * uo[o];
            } else {
#pragma unroll
                for (int o = 0; o < Oc; ++o) acc[o] += 0.1f * uo[o];
            }
        }
#pragma unroll
        for (int o = 0; o < Oc; ++o) {
            float a = acc[o];
            a += __shfl_xor(a, 16);
            a += __shfl_xor(a, 32);
            if (lane < 16) red[wid * ODc + o * 16 + lane] = a;
        }
        __syncthreads();
        if (t < ODc) {
            float s = 0.f;
#pragma unroll
            for (int w = 0; w < 16; ++w) s += red[w * ODc + t];
            svec[t] = s;
        }
        __syncthreads();
        if (t < Oc) {
            float sq = 0.f;
#pragma unroll
            for (int dd = 0; dd < DOc; ++dd) sq += svec[t * 16 + dd] * svec[t * 16 + dd];
            float sc = sq / ((1.f + sq) * sqrtf(sq));
#pragma unroll
            for (int dd = 0; dd < DOc; ++dd) {
                float v = svec[t * 16 + dd] * sc;
                vcur[t * 16 + dd] = v;
                vsum[t * 16 + dd] += v;
            }
        }
        __syncthreads();
    }
    if (t < ODc) out[(size_t)b * ODc + t] = vcur[t];
}

// ---------------------------------------------------------------- launcher
extern "C" void kernel_launch(void* const* d_in, const int* in_sizes, int n_in,
                              void* d_out, int out_size, void* d_ws, size_t ws_size,
                              hipStream_t stream) {
    (void)in_sizes; (void)n_in; (void)out_size;
    const float* x = (const float*)d_in[0];   // [256,1152,8]
    const float* W = (const float*)d_in[1];   // [1152,10,16,8]
    float* out     = (float*)d_out;           // [256,10,16]

    const size_t PART_B = (size_t)ITILES * Bc * ODc * sizeof(float); // 11.8 MB
    const size_t VSUM_B = (size_t)Bc * ODc * sizeof(float);          // 160 KB

    float* partial = (float*)d_ws;
    float* vsum    = (float*)((char*)d_ws + PART_B);

    if (ws_size >= PART_B + VSUM_B) {
        dim3 pg(ITILES * BT), pb(256);
        hipLaunchKernelGGL((k_pass<0>), pg, pb, 0, stream, x, W, nullptr, partial);
        hipLaunchKernelGGL((k_squash<0>), dim3(Bc), dim3(256), 0, stream,
                           partial, vsum, out, 0.1f);
        hipLaunchKernelGGL((k_pass<1>), pg, pb, 0, stream, x, W, vsum, partial);
        hipLaunchKernelGGL((k_squash<1>), dim3(Bc), dim3(256), 0, stream,
                           partial, vsum, out, 1.f);
        hipLaunchKernelGGL((k_pass<1>), pg, pb, 0, stream, x, W, vsum, partial);
        hipLaunchKernelGGL((k_squash<2>), dim3(Bc), dim3(256), 0, stream,
                           partial, vsum, out, 1.f);
    } else {
        hipLaunchKernelGGL(digitcaps_fallback, dim3(Bc), dim3(1024), 0, stream,
                           x, W, out);
    }
}